// Round 22
// baseline (232.829 us; speedup 1.0000x reference)
//
#include <hip/hip_runtime.h>
#include <math.h>

#define N_NODES 100000
#define N_EDGES 1600000
#define F_IN 512
#define HD 64                    // H*D = 8*8
#define CC 7
#define NKT (F_IN / 32)                // 16 K-steps for MFMA GEMM1
#define BS 64                          // dst nodes per bucket
#define NBK ((N_NODES + BS - 1) / BS)  // 1563 buckets
#define ECAP 2048                      // per-bucket edge capacity (LDS staging)
#define SCHUNK 4096                    // edges per binscatter block
#define SBLK ((N_EDGES + SCHUNK - 1) / SCHUNK)   // 391 binscatter blocks
#define NGRP 16                        // chunk groups: depth 391 -> ~25 per counter
#define GRPC ((SBLK + NGRP - 1) / NGRP)          // 25 chunks per group
#define GCAP 128                       // capacity per (bucket,group) region (mean 65, +7.7sig)
#define GEMMBLKS ((N_NODES + 63) / 64)           // 1563 gemm blocks
#define W1WORK (NKT * 4 * 64)                    // 4096 w1prep items

typedef __attribute__((ext_vector_type(8))) short short8;
typedef __attribute__((ext_vector_type(4))) float f32x4;

// float -> bf16 bits, round-to-nearest-even
__device__ inline unsigned short f2bf(float f) {
    union { float f; unsigned u; } v; v.f = f;
    unsigned u = v.u;
    return (unsigned short)((u + 0x7fffu + ((u >> 16) & 1u)) >> 16);
}
__device__ inline float bf2f(unsigned short b) {
    union { unsigned u; float f; } v; v.u = ((unsigned)b) << 16;
    return v.f;
}

// ---- prep: blocks 0..15 convert W1 to B-fragment order; block 16 zeros gcur ----
__global__ __launch_bounds__(256) void prep_kernel(const float* __restrict__ W1,
                                                   unsigned short* __restrict__ wf,
                                                   int* __restrict__ gcur) {
    if (blockIdx.x == 16) {
        for (int i = threadIdx.x; i < NBK * NGRP; i += 256) gcur[i] = 0;
        return;
    }
    int t = blockIdx.x * 256 + threadIdx.x;       // [0, W1WORK)
    if (t >= W1WORK) return;
    int lane = t & 63;
    int ct = (t >> 6) & 3;
    int kt = t >> 8;
    int k0 = kt * 32 + (lane >> 4) * 8;
    int col = ct * 16 + (lane & 15);
    unsigned short* dst = wf + (size_t)t * 8;
    #pragma unroll
    for (int j = 0; j < 8; ++j) dst[j] = f2bf(W1[(k0 + j) * HD + col]);
}

// --- fused: blocks [0,SBLK) = binscatter (grouped regions); rest = GEMM1+att1 ---
// chunk-grouping cuts the per-counter atomic chain depth 391 -> ~25 while
// keeping 391-block scatter parallelism; binning hides under the MFMA GEMM.
__global__ __launch_bounds__(256) void fused_kernel(
        const int* __restrict__ ei, int* __restrict__ gcur, int* __restrict__ pairs,
        const float* __restrict__ x, const unsigned short* __restrict__ wf,
        const float* __restrict__ a1s, const float* __restrict__ a1d,
        unsigned short* __restrict__ h1b, float* __restrict__ als,
        float* __restrict__ ald) {
    __shared__ float ls[64 * 65];                  // 16.64 KB; reused as ints by binscatter
    const int bid = blockIdx.x;
    const int tid = threadIdx.x;
    if (bid < SBLK) {
        // ---------------- binscatter (packed 4B pairs, grouped regions) ----------------
        int* cnt = (int*)ls;                       // [NBK]
        int* bas = cnt + NBK;                      // [NBK]
        const int g = bid / GRPC;                  // this chunk's group
        const int e0 = bid * SCHUNK;
        int e1 = e0 + SCHUNK; if (e1 > N_EDGES) e1 = N_EDGES;
        for (int b = tid; b < NBK; b += 256) cnt[b] = 0;
        __syncthreads();
        for (int i = e0 + tid; i < e1; i += 256)
            atomicAdd(&cnt[ei[N_EDGES + i] >> 6], 1);
        __syncthreads();
        // staggered reserve on per-(bucket,group) counters: chain depth ~25
        const int boff = (bid * 263) % NBK;
        for (int bb = tid; bb < NBK; bb += 256) {
            int b = bb + boff; if (b >= NBK) b -= NBK;
            int c = cnt[b];
            bas[b] = c ? atomicAdd(&gcur[b * NGRP + g], c) : 0;
            cnt[b] = 0;                            // reuse as local cursor
        }
        __syncthreads();
        for (int i = e0 + tid; i < e1; i += 256) {
            int s = ei[i];
            int t = ei[N_EDGES + i];
            int b = t >> 6;
            int pos = bas[b] + atomicAdd(&cnt[b], 1);
            if (pos < GCAP)
                pairs[((size_t)b * NGRP + g) * GCAP + pos] = (s << 6) | (t & (BS - 1));
        }
        return;
    }
    // ---------------- GEMM1 (MFMA) + fused att1 ----------------
    const int gb = bid - SBLK;
    const int wave = tid >> 6;
    const int lane = tid & 63;
    int arow = gb * 64 + wave * 16 + (lane & 15);
    if (arow >= N_NODES) arow = N_NODES - 1;       // clamp for load only
    const float* xp = x + (size_t)arow * F_IN + (lane >> 4) * 8;
    const short8* wp = (const short8*)wf;

    f32x4 acc[4] = {};
    #pragma unroll 4
    for (int kt = 0; kt < NKT; ++kt) {
        f32x4 a0 = *(const f32x4*)(xp + kt * 32);
        f32x4 a1 = *(const f32x4*)(xp + kt * 32 + 4);
        union { short8 s; unsigned short u[8]; } af;
        af.u[0] = f2bf(a0.x); af.u[1] = f2bf(a0.y);
        af.u[2] = f2bf(a0.z); af.u[3] = f2bf(a0.w);
        af.u[4] = f2bf(a1.x); af.u[5] = f2bf(a1.y);
        af.u[6] = f2bf(a1.z); af.u[7] = f2bf(a1.w);
        #pragma unroll
        for (int ct = 0; ct < 4; ++ct) {
            short8 bf = wp[kt * 256 + ct * 64 + lane];
            acc[ct] = __builtin_amdgcn_mfma_f32_16x16x32_bf16(af.s, bf, acc[ct], 0, 0, 0);
        }
    }
    // C/D layout: col = lane&15, row = (lane>>4)*4 + r
    const int lrow_base = wave * 16 + (lane >> 4) * 4;
    const int ocol = lane & 15;
    #pragma unroll
    for (int ct = 0; ct < 4; ++ct) {
        #pragma unroll
        for (int r = 0; r < 4; ++r) {
            int lrow = lrow_base + r;
            int orow = gb * 64 + lrow;
            ls[lrow * 65 + ct * 16 + ocol] = acc[ct][r];
            if (orow < N_NODES)
                h1b[(size_t)orow * HD + ct * 16 + ocol] = f2bf(acc[ct][r]);
        }
    }
    __syncthreads();
    // attention halves: 512 (row,head) tasks over 256 threads
    #pragma unroll
    for (int task = tid; task < 64 * 8; task += 256) {
        int r = task >> 3, h = task & 7;
        int node = gb * 64 + r;
        if (node < N_NODES) {
            float s = 0.f, d = 0.f;
            #pragma unroll
            for (int k = 0; k < 8; ++k) {
                float v = ls[r * 65 + h * 8 + k];
                s += v * a1s[h * 8 + k];
                d += v * a1d[h * 8 + k];
            }
            als[node * 8 + h] = s;
            ald[node * 8 + h] = d;
        }
    }
}

// --- sortcsr: concat 16 group regions + LDS counting sort -> csr_src, rowptr ---
__global__ __launch_bounds__(256) void sortcsr_kernel(const int* __restrict__ gcur,
                                                      const int* __restrict__ pairs,
                                                      int* __restrict__ csr_src,
                                                      int* __restrict__ rowptr,
                                                      int* __restrict__ rowcnt) {
    __shared__ int stg[ECAP];                     // contiguous staging of grouped pairs
    __shared__ int srcl[ECAP];
    __shared__ int cnt[BS];
    __shared__ int start[BS];
    __shared__ int goff[NGRP + 1];
    const int tid = threadIdx.x;
    const int lane = tid & 63;
    const int b = blockIdx.x;
    const int n0 = b * BS;
    const size_t bbase = (size_t)b * ECAP;
    if (tid == 0) {
        int off = 0;
        #pragma unroll
        for (int g = 0; g < NGRP; ++g) {
            goff[g] = off;
            int cg = gcur[b * NGRP + g];
            if (cg > GCAP) cg = GCAP;
            off += cg;
        }
        goff[NGRP] = off;
    }
    if (tid < BS) cnt[tid] = 0;
    __syncthreads();
    const int ne = goff[NGRP];
    #pragma unroll
    for (int g = 0; g < NGRP; ++g) {              // disjoint writes, no sync needed
        int o = goff[g], cg = goff[g + 1] - o;
        const int* gp = pairs + ((size_t)b * NGRP + g) * GCAP;
        for (int k = tid; k < cg; k += 256) stg[o + k] = gp[k];
    }
    __syncthreads();
    for (int k = tid; k < ne; k += 256)
        atomicAdd(&cnt[stg[k] & (BS - 1)], 1);
    __syncthreads();
    if (tid < 64) {
        int a = cnt[lane];
        int xx = a;
        #pragma unroll
        for (int o = 1; o < 64; o <<= 1) { int u = __shfl_up(xx, o, 64); if (lane >= o) xx += u; }
        start[lane] = xx - a;
        cnt[lane] = 0;                                // reuse as cursor
    }
    __syncthreads();
    for (int k = tid; k < ne; k += 256) {
        int v = stg[k];
        int ln = v & (BS - 1);
        int pos = start[ln] + atomicAdd(&cnt[ln], 1);
        srcl[pos] = v >> 6;
    }
    __syncthreads();
    // coalesced writeback + per-node metadata
    for (int k = tid; k < ne; k += 256) csr_src[bbase + k] = srcl[k];
    if (tid < BS) {
        int node = n0 + tid;
        if (node < N_NODES) {
            rowptr[node] = (int)bbase + start[tid];
            rowcnt[node] = cnt[tid];
        }
    }
}

// ---- gather layer 1: flat per-node wave, shfl-dedup p, batched loads --------
__global__ __launch_bounds__(256) void gather1_kernel(
        const int* __restrict__ rowptr, const int* __restrict__ rowcnt,
        const int* __restrict__ csr_src,
        const float* __restrict__ als, const float* __restrict__ ald,
        const unsigned short* __restrict__ h1b, const float* __restrict__ b1,
        const float* __restrict__ W2, const float* __restrict__ a2s,
        const float* __restrict__ a2d,
        unsigned short* __restrict__ g2b, float* __restrict__ al2s,
        float* __restrict__ al2d) {
    int node = (blockIdx.x * 256 + threadIdx.x) >> 6;    // one wave per node
    if (node >= N_NODES) return;
    const int lane = threadIdx.x & 63;
    const int h = lane >> 3;
    const int e8 = lane & 7, base8 = lane & 56;
    const int rs = rowptr[node], ncnt = rowcnt[node];
    const float aldt = ald[node * 8 + h];
    float e = als[node * 8 + h] + aldt;                  // self loop
    e = (e >= 0.f) ? e : 0.2f * e;
    float p = __expf(e);
    float acc = p * bf2f(h1b[(size_t)node * HD + lane]);
    float z = p;
    int k = 0;
    for (; k + 8 <= ncnt; k += 8) {
        int s_own = csr_src[rs + k + e8];                // coalesced 32B/group
        int se[8];
        #pragma unroll
        for (int q = 0; q < 8; ++q) se[q] = __shfl(s_own, base8 | q, 64);
        float ve[8];
        #pragma unroll
        for (int q = 0; q < 8; ++q) ve[q] = bf2f(h1b[(size_t)se[q] * HD + lane]);
        float ee = als[s_own * 8 + h] + aldt;
        ee = (ee >= 0.f) ? ee : 0.2f * ee;
        float pv = __expf(ee);
        #pragma unroll
        for (int q = 0; q < 8; ++q) {
            float pe = __shfl(pv, base8 | q, 64);
            z += pe;
            acc = fmaf(pe, ve[q], acc);
        }
    }
    if (k < ncnt) {                                      // masked final chunk
        const int m = ncnt - k;
        int idx = rs + k + ((e8 < m) ? e8 : (m - 1));
        int s_own = csr_src[idx];
        int se[8];
        #pragma unroll
        for (int q = 0; q < 8; ++q) se[q] = __shfl(s_own, base8 | q, 64);
        float ee = als[s_own * 8 + h] + aldt;
        ee = (ee >= 0.f) ? ee : 0.2f * ee;
        float pv = __expf(ee);
        for (int q = 0; q < m; ++q) {
            float pe = __shfl(pv, base8 | q, 64);
            float ve = bf2f(h1b[(size_t)se[q] * HD + lane]);
            z += pe;
            acc = fmaf(pe, ve, acc);
        }
    }
    // epilogue: alpha-normalize + bias + ELU
    float v = acc / z + b1[lane];
    v = (v > 0.f) ? v : (__expf(v) - 1.f);
    // fused GEMM2: g[c] = sum_j v_j * W2[j][c]  (butterfly over the wave)
    float w[CC];
    #pragma unroll
    for (int c = 0; c < CC; ++c) w[c] = W2[lane * CC + c];
    float g[CC];
    #pragma unroll
    for (int c = 0; c < CC; ++c) {
        float r = v * w[c];
        #pragma unroll
        for (int d = 1; d < 64; d <<= 1) r += __shfl_xor(r, d, 64);
        g[c] = r;
    }
    float s2 = 0.f, d2 = 0.f;
    #pragma unroll
    for (int c = 0; c < CC; ++c) { s2 += g[c] * a2s[c]; d2 += g[c] * a2d[c]; }
    if (lane < CC) g2b[(size_t)node * 8 + lane] = f2bf(g[lane]);
    if (lane == CC) g2b[(size_t)node * 8 + CC] = 0;
    if (lane == 8) al2s[node] = s2;
    if (lane == 9) al2d[node] = d2;
}

// ---- gather layer 2: flat 8-lane groups, shfl-dedup p, log_softmax ----------
__global__ __launch_bounds__(256) void gather2_kernel(
        const int* __restrict__ rowptr, const int* __restrict__ rowcnt,
        const int* __restrict__ csr_src,
        const float* __restrict__ al2s, const float* __restrict__ al2d,
        const unsigned short* __restrict__ g2b, const float* __restrict__ b2,
        float* __restrict__ out) {
    int gid = blockIdx.x * 256 + threadIdx.x;
    int n = gid >> 3, c = gid & 7;
    if (n >= N_NODES) return;
    const int lane = threadIdx.x & 63;
    const int base8 = lane & 56;
    const int rs = rowptr[n], ncnt = rowcnt[n];
    const float adn = al2d[n];
    float e = al2s[n] + adn;                             // self loop
    e = (e >= 0.f) ? e : 0.2f * e;
    float p = __expf(e);
    float acc = p * bf2f(g2b[(size_t)n * 8 + c]);
    float z = p;
    int k = 0;
    for (; k + 8 <= ncnt; k += 8) {
        int s_own = csr_src[rs + k + c];
        int se[8];
        #pragma unroll
        for (int q = 0; q < 8; ++q) se[q] = __shfl(s_own, base8 | q, 64);
        float ve[8];
        #pragma unroll
        for (int q = 0; q < 8; ++q) ve[q] = bf2f(g2b[(size_t)se[q] * 8 + c]);
        float ee = al2s[s_own] + adn;
        ee = (ee >= 0.f) ? ee : 0.2f * ee;
        float pv = __expf(ee);
        #pragma unroll
        for (int q = 0; q < 8; ++q) {
            float pe = __shfl(pv, base8 | q, 64);
            z += pe;
            acc = fmaf(pe, ve[q], acc);
        }
    }
    if (k < ncnt) {
        const int m = ncnt - k;
        int idx = rs + k + ((c < m) ? c : (m - 1));
        int s_own = csr_src[idx];
        int se[8];
        #pragma unroll
        for (int q = 0; q < 8; ++q) se[q] = __shfl(s_own, base8 | q, 64);
        float ee = al2s[s_own] + adn;
        ee = (ee >= 0.f) ? ee : 0.2f * ee;
        float pv = __expf(ee);
        for (int q = 0; q < m; ++q) {
            float pe = __shfl(pv, base8 | q, 64);
            float ve = bf2f(g2b[(size_t)se[q] * 8 + c]);
            z += pe;
            acc = fmaf(pe, ve, acc);
        }
    }
    float o = (c < CC) ? (acc / z + b2[c]) : -1e30f;
    float m2 = o;
    #pragma unroll
    for (int d = 1; d < 8; d <<= 1) m2 = fmaxf(m2, __shfl_xor(m2, d, 8));
    float ex = (c < CC) ? __expf(o - m2) : 0.f;
    float sum = ex;
    #pragma unroll
    for (int d = 1; d < 8; d <<= 1) sum += __shfl_xor(sum, d, 8);
    float lse = m2 + __logf(sum);
    if (c < CC) out[(size_t)n * CC + c] = o - lse;
}

extern "C" void kernel_launch(void* const* d_in, const int* in_sizes, int n_in,
                              void* d_out, int out_size, void* d_ws, size_t ws_size,
                              hipStream_t stream) {
    const float* x   = (const float*)d_in[0];
    const int*   ei  = (const int*)d_in[1];
    const float* W1  = (const float*)d_in[2];
    const float* a1s = (const float*)d_in[3];
    const float* a1d = (const float*)d_in[4];
    const float* b1  = (const float*)d_in[5];
    const float* W2  = (const float*)d_in[6];
    const float* a2s = (const float*)d_in[7];
    const float* a2d = (const float*)d_in[8];
    const float* b2  = (const float*)d_in[9];
    float* out = (float*)d_out;

    // byte-offset workspace allocator (64B aligned)
    char* base = (char*)d_ws;
    size_t off = 0;
    auto alloc = [&](size_t bytes) { char* p = base + off; off = (off + bytes + 63) & ~(size_t)63; return p; };
    unsigned short* h1b = (unsigned short*)alloc((size_t)N_NODES * HD * 2);
    unsigned short* wf  = (unsigned short*)alloc((size_t)W1WORK * 8 * 2);
    float* als  = (float*)alloc((size_t)N_NODES * 8 * 4);
    float* ald  = (float*)alloc((size_t)N_NODES * 8 * 4);
    unsigned short* g2b = (unsigned short*)alloc((size_t)N_NODES * 8 * 2);
    float* al2s = (float*)alloc((size_t)N_NODES * 4);
    float* al2d = (float*)alloc((size_t)N_NODES * 4);
    int* gcur   = (int*)alloc((size_t)NBK * NGRP * 4);   // per-(bucket,group) cursors
    int* rowptr = (int*)alloc((size_t)N_NODES * 4);
    int* rowcnt = (int*)alloc((size_t)N_NODES * 4);
    int* csr_src= (int*)alloc((size_t)NBK * ECAP * 4);
    int* pairs  = (int*)alloc((size_t)NBK * NGRP * GCAP * 4);  // packed (s<<6)|ln

    prep_kernel<<<17, 256, 0, stream>>>(W1, wf, gcur);
    fused_kernel<<<SBLK + GEMMBLKS, 256, 0, stream>>>(
        ei, gcur, pairs, x, wf, a1s, a1d, h1b, als, ald);
    sortcsr_kernel<<<NBK, 256, 0, stream>>>(gcur, pairs, csr_src, rowptr, rowcnt);
    gather1_kernel<<<(N_NODES * 64 + 255) / 256, 256, 0, stream>>>(
        rowptr, rowcnt, csr_src, als, ald, h1b, b1, W2, a2s, a2d, g2b, al2s, al2d);
    gather2_kernel<<<(N_NODES * 8 + 255) / 256, 256, 0, stream>>>(
        rowptr, rowcnt, csr_src, al2s, al2d, g2b, b2, out);
}

// Round 23
// 195.818 us; speedup vs baseline: 1.1890x; 1.1890x over previous
//
#include <hip/hip_runtime.h>
#include <math.h>

#define N_NODES 100000
#define N_EDGES 1600000
#define F_IN 512
#define HD 64                    // H*D = 8*8
#define CC 7
#define NKT (F_IN / 32)                // 16 K-steps for MFMA GEMM1
#define BS 64                          // dst nodes per bucket
#define NBK ((N_NODES + BS - 1) / BS)  // 1563 buckets
#define ECAP 2048                      // fixed edge capacity per bucket (mean 1024, +32 sigma)
#define SCHUNK 4096                    // edges per binscatter block
#define SBLK ((N_EDGES + SCHUNK - 1) / SCHUNK)   // 391 binscatter blocks
#define GEMMBLKS ((N_NODES + 63) / 64)           // 1563 gemm blocks
#define W1WORK (NKT * 4 * 64)                    // 4096 w1prep items

typedef __attribute__((ext_vector_type(8))) short short8;
typedef __attribute__((ext_vector_type(4))) float f32x4;

// float -> bf16 bits, round-to-nearest-even
__device__ inline unsigned short f2bf(float f) {
    union { float f; unsigned u; } v; v.f = f;
    unsigned u = v.u;
    return (unsigned short)((u + 0x7fffu + ((u >> 16) & 1u)) >> 16);
}
__device__ inline float bf2f(unsigned short b) {
    union { unsigned u; float f; } v; v.u = ((unsigned)b) << 16;
    return v.f;
}

// ---- prep: blocks 0..15 convert W1 to B-fragment order; block 16 zeros bcur ----
__global__ __launch_bounds__(256) void prep_kernel(const float* __restrict__ W1,
                                                   unsigned short* __restrict__ wf,
                                                   int* __restrict__ bcur) {
    if (blockIdx.x == 16) {
        for (int i = threadIdx.x; i < NBK; i += 256) bcur[i] = 0;
        return;
    }
    int t = blockIdx.x * 256 + threadIdx.x;       // [0, W1WORK)
    if (t >= W1WORK) return;
    int lane = t & 63;
    int ct = (t >> 6) & 3;
    int kt = t >> 8;
    int k0 = kt * 32 + (lane >> 4) * 8;
    int col = ct * 16 + (lane & 15);
    unsigned short* dst = wf + (size_t)t * 8;
    #pragma unroll
    for (int j = 0; j < 8; ++j) dst[j] = f2bf(W1[(k0 + j) * HD + col]);
}

// --- fused: INTERLEAVED block mapping (bid%5==0 -> binscatter, else GEMM1+att1) ---
// interleaving co-schedules latency-bound binning WITH the BW-bound MFMA GEMM
// across the whole dispatch (block IDs launch roughly in order).
__global__ __launch_bounds__(256) void fused_kernel(
        const int* __restrict__ ei, int* __restrict__ bcur, int* __restrict__ pairs,
        const float* __restrict__ x, const unsigned short* __restrict__ wf,
        const float* __restrict__ a1s, const float* __restrict__ a1d,
        unsigned short* __restrict__ h1b, float* __restrict__ als,
        float* __restrict__ ald) {
    __shared__ float ls[64 * 65];                  // 16.64 KB; reused as ints by binscatter
    const int bid = blockIdx.x;
    const int tid = threadIdx.x;
    if (bid % 5 == 0) {
        // ---------------- binscatter (packed 4B pairs) ----------------
        const int sb = bid / 5;                    // scatter id [0, SBLK)
        int* cnt = (int*)ls;                       // [NBK]
        int* bas = cnt + NBK;                      // [NBK]
        const int e0 = sb * SCHUNK;
        int e1 = e0 + SCHUNK; if (e1 > N_EDGES) e1 = N_EDGES;
        for (int b = tid; b < NBK; b += 256) cnt[b] = 0;
        __syncthreads();
        for (int i = e0 + tid; i < e1; i += 256)
            atomicAdd(&cnt[ei[N_EDGES + i] >> 6], 1);
        __syncthreads();
        // staggered reserve: block-dependent start offset spreads contention
        const int boff = (sb * 263) % NBK;
        for (int bb = tid; bb < NBK; bb += 256) {
            int b = bb + boff; if (b >= NBK) b -= NBK;
            int c = cnt[b];
            bas[b] = c ? atomicAdd(&bcur[b], c) : 0;
            cnt[b] = 0;                            // reuse as local cursor
        }
        __syncthreads();
        for (int i = e0 + tid; i < e1; i += 256) {
            int s = ei[i];
            int t = ei[N_EDGES + i];
            int b = t >> 6;
            int pos = bas[b] + atomicAdd(&cnt[b], 1);
            if (pos < ECAP) pairs[(size_t)b * ECAP + pos] = (s << 6) | (t & (BS - 1));
        }
        return;
    }
    // ---------------- GEMM1 (MFMA) + fused att1 ----------------
    const int gb = bid - bid / 5 - 1;              // gemm id [0, GEMMBLKS)
    const int wave = tid >> 6;
    const int lane = tid & 63;
    int arow = gb * 64 + wave * 16 + (lane & 15);
    if (arow >= N_NODES) arow = N_NODES - 1;       // clamp for load only
    const float* xp = x + (size_t)arow * F_IN + (lane >> 4) * 8;
    const short8* wp = (const short8*)wf;

    f32x4 acc[4] = {};
    #pragma unroll 4
    for (int kt = 0; kt < NKT; ++kt) {
        f32x4 a0 = *(const f32x4*)(xp + kt * 32);
        f32x4 a1 = *(const f32x4*)(xp + kt * 32 + 4);
        union { short8 s; unsigned short u[8]; } af;
        af.u[0] = f2bf(a0.x); af.u[1] = f2bf(a0.y);
        af.u[2] = f2bf(a0.z); af.u[3] = f2bf(a0.w);
        af.u[4] = f2bf(a1.x); af.u[5] = f2bf(a1.y);
        af.u[6] = f2bf(a1.z); af.u[7] = f2bf(a1.w);
        #pragma unroll
        for (int ct = 0; ct < 4; ++ct) {
            short8 bf = wp[kt * 256 + ct * 64 + lane];
            acc[ct] = __builtin_amdgcn_mfma_f32_16x16x32_bf16(af.s, bf, acc[ct], 0, 0, 0);
        }
    }
    // C/D layout: col = lane&15, row = (lane>>4)*4 + r
    const int lrow_base = wave * 16 + (lane >> 4) * 4;
    const int ocol = lane & 15;
    #pragma unroll
    for (int ct = 0; ct < 4; ++ct) {
        #pragma unroll
        for (int r = 0; r < 4; ++r) {
            int lrow = lrow_base + r;
            int orow = gb * 64 + lrow;
            ls[lrow * 65 + ct * 16 + ocol] = acc[ct][r];
            if (orow < N_NODES)
                h1b[(size_t)orow * HD + ct * 16 + ocol] = f2bf(acc[ct][r]);
        }
    }
    __syncthreads();
    // attention halves: 512 (row,head) tasks over 256 threads
    #pragma unroll
    for (int task = tid; task < 64 * 8; task += 256) {
        int r = task >> 3, h = task & 7;
        int node = gb * 64 + r;
        if (node < N_NODES) {
            float s = 0.f, d = 0.f;
            #pragma unroll
            for (int k = 0; k < 8; ++k) {
                float v = ls[r * 65 + h * 8 + k];
                s += v * a1s[h * 8 + k];
                d += v * a1d[h * 8 + k];
            }
            als[node * 8 + h] = s;
            ald[node * 8 + h] = d;
        }
    }
}

// --- sortcsr: per-bucket LDS counting sort -> csr_src, rowptr, rowcnt -------
__global__ __launch_bounds__(256) void sortcsr_kernel(const int* __restrict__ bcur,
                                                      const int* __restrict__ pairs,
                                                      int* __restrict__ csr_src,
                                                      int* __restrict__ rowptr,
                                                      int* __restrict__ rowcnt) {
    __shared__ int cnt[BS];
    __shared__ int start[BS];
    __shared__ int srcl[ECAP];
    const int tid = threadIdx.x;
    const int lane = tid & 63;
    const int n0 = blockIdx.x * BS;
    const size_t bbase = (size_t)blockIdx.x * ECAP;
    const int* bp = pairs + bbase;
    int ne = bcur[blockIdx.x]; if (ne > ECAP) ne = ECAP;
    if (tid < BS) cnt[tid] = 0;
    __syncthreads();
    for (int k = tid; k < ne; k += 256)
        atomicAdd(&cnt[bp[k] & (BS - 1)], 1);
    __syncthreads();
    if (tid < 64) {
        int a = cnt[lane];
        int xx = a;
        #pragma unroll
        for (int o = 1; o < 64; o <<= 1) { int u = __shfl_up(xx, o, 64); if (lane >= o) xx += u; }
        start[lane] = xx - a;
        cnt[lane] = 0;                                // reuse as cursor
    }
    __syncthreads();
    for (int k = tid; k < ne; k += 256) {
        int v = bp[k];
        int ln = v & (BS - 1);
        int pos = start[ln] + atomicAdd(&cnt[ln], 1);
        srcl[pos] = v >> 6;
    }
    __syncthreads();
    // coalesced writeback + per-node metadata
    for (int k = tid; k < ne; k += 256) csr_src[bbase + k] = srcl[k];
    if (tid < BS) {
        int node = n0 + tid;
        if (node < N_NODES) {
            rowptr[node] = (int)bbase + start[tid];
            rowcnt[node] = cnt[tid];
        }
    }
}

// ---- gather layer 1: flat per-node wave, shfl-dedup p, batched loads --------
__global__ __launch_bounds__(256) void gather1_kernel(
        const int* __restrict__ rowptr, const int* __restrict__ rowcnt,
        const int* __restrict__ csr_src,
        const float* __restrict__ als, const float* __restrict__ ald,
        const unsigned short* __restrict__ h1b, const float* __restrict__ b1,
        const float* __restrict__ W2, const float* __restrict__ a2s,
        const float* __restrict__ a2d,
        unsigned short* __restrict__ g2b, float* __restrict__ al2s,
        float* __restrict__ al2d) {
    int node = (blockIdx.x * 256 + threadIdx.x) >> 6;    // one wave per node
    if (node >= N_NODES) return;
    const int lane = threadIdx.x & 63;
    const int h = lane >> 3;
    const int e8 = lane & 7, base8 = lane & 56;
    const int rs = rowptr[node], ncnt = rowcnt[node];
    const float aldt = ald[node * 8 + h];
    float e = als[node * 8 + h] + aldt;                  // self loop
    e = (e >= 0.f) ? e : 0.2f * e;
    float p = __expf(e);
    float acc = p * bf2f(h1b[(size_t)node * HD + lane]);
    float z = p;
    int k = 0;
    for (; k + 8 <= ncnt; k += 8) {
        int s_own = csr_src[rs + k + e8];                // coalesced 32B/group
        int se[8];
        #pragma unroll
        for (int q = 0; q < 8; ++q) se[q] = __shfl(s_own, base8 | q, 64);
        float ve[8];
        #pragma unroll
        for (int q = 0; q < 8; ++q) ve[q] = bf2f(h1b[(size_t)se[q] * HD + lane]);
        float ee = als[s_own * 8 + h] + aldt;
        ee = (ee >= 0.f) ? ee : 0.2f * ee;
        float pv = __expf(ee);
        #pragma unroll
        for (int q = 0; q < 8; ++q) {
            float pe = __shfl(pv, base8 | q, 64);
            z += pe;
            acc = fmaf(pe, ve[q], acc);
        }
    }
    if (k < ncnt) {                                      // masked final chunk
        const int m = ncnt - k;
        int idx = rs + k + ((e8 < m) ? e8 : (m - 1));
        int s_own = csr_src[idx];
        int se[8];
        #pragma unroll
        for (int q = 0; q < 8; ++q) se[q] = __shfl(s_own, base8 | q, 64);
        float ee = als[s_own * 8 + h] + aldt;
        ee = (ee >= 0.f) ? ee : 0.2f * ee;
        float pv = __expf(ee);
        for (int q = 0; q < m; ++q) {
            float pe = __shfl(pv, base8 | q, 64);
            float ve = bf2f(h1b[(size_t)se[q] * HD + lane]);
            z += pe;
            acc = fmaf(pe, ve, acc);
        }
    }
    // epilogue: alpha-normalize + bias + ELU
    float v = acc / z + b1[lane];
    v = (v > 0.f) ? v : (__expf(v) - 1.f);
    // fused GEMM2: g[c] = sum_j v_j * W2[j][c]  (butterfly over the wave)
    float w[CC];
    #pragma unroll
    for (int c = 0; c < CC; ++c) w[c] = W2[lane * CC + c];
    float g[CC];
    #pragma unroll
    for (int c = 0; c < CC; ++c) {
        float r = v * w[c];
        #pragma unroll
        for (int d = 1; d < 64; d <<= 1) r += __shfl_xor(r, d, 64);
        g[c] = r;
    }
    float s2 = 0.f, d2 = 0.f;
    #pragma unroll
    for (int c = 0; c < CC; ++c) { s2 += g[c] * a2s[c]; d2 += g[c] * a2d[c]; }
    if (lane < CC) g2b[(size_t)node * 8 + lane] = f2bf(g[lane]);
    if (lane == CC) g2b[(size_t)node * 8 + CC] = 0;
    if (lane == 8) al2s[node] = s2;
    if (lane == 9) al2d[node] = d2;
}

// ---- gather layer 2: flat 8-lane groups, shfl-dedup p, log_softmax ----------
__global__ __launch_bounds__(256) void gather2_kernel(
        const int* __restrict__ rowptr, const int* __restrict__ rowcnt,
        const int* __restrict__ csr_src,
        const float* __restrict__ al2s, const float* __restrict__ al2d,
        const unsigned short* __restrict__ g2b, const float* __restrict__ b2,
        float* __restrict__ out) {
    int gid = blockIdx.x * 256 + threadIdx.x;
    int n = gid >> 3, c = gid & 7;
    if (n >= N_NODES) return;
    const int lane = threadIdx.x & 63;
    const int base8 = lane & 56;
    const int rs = rowptr[n], ncnt = rowcnt[n];
    const float adn = al2d[n];
    float e = al2s[n] + adn;                             // self loop
    e = (e >= 0.f) ? e : 0.2f * e;
    float p = __expf(e);
    float acc = p * bf2f(g2b[(size_t)n * 8 + c]);
    float z = p;
    int k = 0;
    for (; k + 8 <= ncnt; k += 8) {
        int s_own = csr_src[rs + k + c];
        int se[8];
        #pragma unroll
        for (int q = 0; q < 8; ++q) se[q] = __shfl(s_own, base8 | q, 64);
        float ve[8];
        #pragma unroll
        for (int q = 0; q < 8; ++q) ve[q] = bf2f(g2b[(size_t)se[q] * 8 + c]);
        float ee = al2s[s_own] + adn;
        ee = (ee >= 0.f) ? ee : 0.2f * ee;
        float pv = __expf(ee);
        #pragma unroll
        for (int q = 0; q < 8; ++q) {
            float pe = __shfl(pv, base8 | q, 64);
            z += pe;
            acc = fmaf(pe, ve[q], acc);
        }
    }
    if (k < ncnt) {
        const int m = ncnt - k;
        int idx = rs + k + ((c < m) ? c : (m - 1));
        int s_own = csr_src[idx];
        int se[8];
        #pragma unroll
        for (int q = 0; q < 8; ++q) se[q] = __shfl(s_own, base8 | q, 64);
        float ee = al2s[s_own] + adn;
        ee = (ee >= 0.f) ? ee : 0.2f * ee;
        float pv = __expf(ee);
        for (int q = 0; q < m; ++q) {
            float pe = __shfl(pv, base8 | q, 64);
            float ve = bf2f(g2b[(size_t)se[q] * 8 + c]);
            z += pe;
            acc = fmaf(pe, ve, acc);
        }
    }
    float o = (c < CC) ? (acc / z + b2[c]) : -1e30f;
    float m2 = o;
    #pragma unroll
    for (int d = 1; d < 8; d <<= 1) m2 = fmaxf(m2, __shfl_xor(m2, d, 8));
    float ex = (c < CC) ? __expf(o - m2) : 0.f;
    float sum = ex;
    #pragma unroll
    for (int d = 1; d < 8; d <<= 1) sum += __shfl_xor(sum, d, 8);
    float lse = m2 + __logf(sum);
    if (c < CC) out[(size_t)n * CC + c] = o - lse;
}

extern "C" void kernel_launch(void* const* d_in, const int* in_sizes, int n_in,
                              void* d_out, int out_size, void* d_ws, size_t ws_size,
                              hipStream_t stream) {
    const float* x   = (const float*)d_in[0];
    const int*   ei  = (const int*)d_in[1];
    const float* W1  = (const float*)d_in[2];
    const float* a1s = (const float*)d_in[3];
    const float* a1d = (const float*)d_in[4];
    const float* b1  = (const float*)d_in[5];
    const float* W2  = (const float*)d_in[6];
    const float* a2s = (const float*)d_in[7];
    const float* a2d = (const float*)d_in[8];
    const float* b2  = (const float*)d_in[9];
    float* out = (float*)d_out;

    // byte-offset workspace allocator (64B aligned)
    char* base = (char*)d_ws;
    size_t off = 0;
    auto alloc = [&](size_t bytes) { char* p = base + off; off = (off + bytes + 63) & ~(size_t)63; return p; };
    unsigned short* h1b = (unsigned short*)alloc((size_t)N_NODES * HD * 2);
    unsigned short* wf  = (unsigned short*)alloc((size_t)W1WORK * 8 * 2);
    float* als  = (float*)alloc((size_t)N_NODES * 8 * 4);
    float* ald  = (float*)alloc((size_t)N_NODES * 8 * 4);
    unsigned short* g2b = (unsigned short*)alloc((size_t)N_NODES * 8 * 2);
    float* al2s = (float*)alloc((size_t)N_NODES * 4);
    float* al2d = (float*)alloc((size_t)N_NODES * 4);
    int* bcur   = (int*)alloc((size_t)NBK * 4);
    int* rowptr = (int*)alloc((size_t)N_NODES * 4);
    int* rowcnt = (int*)alloc((size_t)N_NODES * 4);
    int* csr_src= (int*)alloc((size_t)NBK * ECAP * 4);
    int* pairs  = (int*)alloc((size_t)NBK * ECAP * 4);   // packed (s<<6)|ln

    prep_kernel<<<17, 256, 0, stream>>>(W1, wf, bcur);
    fused_kernel<<<SBLK + GEMMBLKS, 256, 0, stream>>>(
        ei, bcur, pairs, x, wf, a1s, a1d, h1b, als, ald);
    sortcsr_kernel<<<NBK, 256, 0, stream>>>(bcur, pairs, csr_src, rowptr, rowcnt);
    gather1_kernel<<<(N_NODES * 64 + 255) / 256, 256, 0, stream>>>(
        rowptr, rowcnt, csr_src, als, ald, h1b, b1, W2, a2s, a2d, g2b, al2s, al2d);
    gather2_kernel<<<(N_NODES * 8 + 255) / 256, 256, 0, stream>>>(
        rowptr, rowcnt, csr_src, al2s, al2d, g2b, b2, out);
}